// Round 5
// baseline (108.328 us; speedup 1.0000x reference)
//
#include <hip/hip_runtime.h>
#include <math.h>

#define NQ   12
#define NL   6
#define BATCH 256
#define NT   512       // 8 waves/block, 1 block/CU
#define PI2  9.869604401089358f   // pi*pi

typedef float v2f __attribute__((ext_vector_type(2)));

__device__ __forceinline__ float geluf(float x) {
    return 0.5f * x * (1.0f + erff(x * 0.70710678118654752f));
}

// LDS pad: P(x) = x + (x>>4) + (x>>8); additive over disjoint-bit splits.
__device__ __forceinline__ int Pad(int x) { return x + (x >> 4) + (x >> 8); }

// ring-CNOT gather map (GF(2)-linear; HW-verified R1-R4)
__device__ __forceinline__ int gmap(int j) {
    return ((j ^ (j >> 1)) & 0x3FF)
         | ((((j >> 10) ^ (j >> 11) ^ j) & 1) << 10)
         | ((((j >> 11) ^ j) & 1) << 11);
}

__device__ __forceinline__ v2f mk2(float a, float b) { v2f r; r.x = a; r.y = b; return r; }
__device__ __forceinline__ v2f spl(float s)          { v2f r; r.x = s; r.y = s; return r; }
__device__ __forceinline__ v2f swn(v2f x)            { v2f r; r.x = -x.y; r.y = x.x; return r; }
// complex mul / mul-add on packed v2f (contracts to v_pk_fma_f32)
__device__ __forceinline__ v2f cml(v2f u, v2f x)          { return spl(u.x) * x + spl(u.y) * swn(x); }
__device__ __forceinline__ v2f cma(v2f u, v2f x, v2f acc) { return acc + spl(u.x) * x + spl(u.y) * swn(x); }

// butterfly: (x0,x1) <- U * (x0,x1)
__device__ __forceinline__ void bf(v2f& x0, v2f& x1, const v2f* U) {
    v2f o0 = cma(U[1], x1, cml(U[0], x0));
    v2f o1 = cma(U[3], x1, cml(U[2], x0));
    x0 = o0; x1 = o1;
}

__device__ __forceinline__ void gate_reg(v2f* a, const v2f* U, int bit) {
    #pragma unroll
    for (int m = 0; m < 8; m++) {
        if (m & bit) continue;
        bf(a[m], a[m | bit], U);
    }
}

// DPP cross-lane gate: quad_perm xor1=0xB1, xor2=0x4E, row_ror:8=xor8=0x128 (HW-verified R3/R4)
template<int CTRL>
__device__ __forceinline__ v2f dppv(v2f v) {
    int x = __builtin_amdgcn_update_dpp(0, __float_as_int(v.x), CTRL, 0xF, 0xF, true);
    int y = __builtin_amdgcn_update_dpp(0, __float_as_int(v.y), CTRL, 0xF, 0xF, true);
    return mk2(__int_as_float(x), __int_as_float(y));
}
template<int CTRL>
__device__ __forceinline__ void gate_dpp(v2f* a, const v2f* U, bool sel) {
    const v2f cA = sel ? U[3] : U[0];
    const v2f cB = sel ? U[2] : U[1];
    #pragma unroll
    for (int m = 0; m < 8; m++) {
        v2f v = dppv<CTRL>(a[m]);
        a[m] = cma(cB, v, cml(cA, a[m]));
    }
}

__global__ __launch_bounds__(NT)
void qpu_kernel(const float* __restrict__ x,   const float* __restrict__ W1, const float* __restrict__ b1,
                const float* __restrict__ g_ln, const float* __restrict__ b_ln,
                const float* __restrict__ W2,  const float* __restrict__ b2,
                const float* __restrict__ W3,  const float* __restrict__ b3,
                const float* __restrict__ qw,  const float* __restrict__ W4, const float* __restrict__ b4,
                const float* __restrict__ W5,  const float* __restrict__ b5,
                float* __restrict__ out)
{
    __shared__ v2f   bufA[4368];        // Pad(4095)=4365; ring-RT buffer
    __shared__ v2f   bufB[4368];        // sigma-RT buffer
    __shared__ v2f   Um[NL * NQ * 4];
    __shared__ float xs[256];
    __shared__ float pr[1280];
    __shared__ float h1n[128];
    __shared__ float h2s[64];
    __shared__ float xqs[NQ];
    __shared__ float musd[2];
    __shared__ float qv[3];
    __shared__ float h4s[32];
    __shared__ float zred[8][3];

    const int t = threadIdx.x;
    const int b = blockIdx.x;

    // ----------------- front-end MLP (split-K) -----------------
    if (t < 256) xs[t] = x[b * 256 + t];
    __syncthreads();

    // h1: 128 outs x 4 parts x 64 elems
    {
        const int o = t >> 2, part = t & 3;
        const float4* w  = (const float4*)(W1 + o * 256) + part * 16;
        const float*  xp = xs + part * 64;
        float a0 = 0.f, a1 = 0.f, a2 = 0.f, a3 = 0.f;
        #pragma unroll
        for (int k = 0; k < 16; k++) {
            float4 wv = w[k];
            a0 = fmaf(wv.x, xp[4 * k + 0], a0);
            a1 = fmaf(wv.y, xp[4 * k + 1], a1);
            a2 = fmaf(wv.z, xp[4 * k + 2], a2);
            a3 = fmaf(wv.w, xp[4 * k + 3], a3);
        }
        pr[o * 5 + part] = (a0 + a1) + (a2 + a3);
    }
    __syncthreads();
    if (t < 128) {
        float s = pr[t * 5 + 0] + pr[t * 5 + 1] + pr[t * 5 + 2] + pr[t * 5 + 3];
        h1n[t] = geluf(s + b1[t]);
    }
    __syncthreads();

    if (t < 64) {
        float v0 = h1n[t], v1 = h1n[t + 64];
        float s1 = v0 + v1;
        float s2 = fmaf(v0, v0, v1 * v1);
        #pragma unroll
        for (int off = 32; off > 0; off >>= 1) {
            s1 += __shfl_down(s1, off);
            s2 += __shfl_down(s2, off);
        }
        if (t == 0) {
            float mu  = s1 * (1.f / 128.f);
            float var = s2 * (1.f / 128.f) - mu * mu;
            musd[0] = mu;
            musd[1] = rsqrtf(var + 1e-5f);
        }
    }
    __syncthreads();
    if (t < 128) h1n[t] = (h1n[t] - musd[0]) * musd[1] * g_ln[t] + b_ln[t];
    __syncthreads();

    // h2: 64 outs x 8 parts x 16 elems
    {
        const int o = t >> 3, part = t & 7;
        if (o < 64) {
            const float4* w  = (const float4*)(W2 + o * 128) + part * 4;
            const float*  hp = h1n + part * 16;
            float a0 = 0.f, a1 = 0.f, a2 = 0.f, a3 = 0.f;
            #pragma unroll
            for (int k = 0; k < 4; k++) {
                float4 wv = w[k];
                a0 = fmaf(wv.x, hp[4 * k + 0], a0);
                a1 = fmaf(wv.y, hp[4 * k + 1], a1);
                a2 = fmaf(wv.z, hp[4 * k + 2], a2);
                a3 = fmaf(wv.w, hp[4 * k + 3], a3);
            }
            pr[o * 9 + part] = (a0 + a1) + (a2 + a3);
        }
    }
    __syncthreads();
    if (t < 64) {
        float s = 0.f;
        #pragma unroll
        for (int k = 0; k < 8; k++) s += pr[t * 9 + k];
        h2s[t] = geluf(s + b2[t]);
    }
    __syncthreads();

    // xq: 12 outs x 8 parts x 8 elems
    if (t < 96) {
        const int o = t >> 3, part = t & 7;
        const float4* w  = (const float4*)(W3 + o * 64) + part * 2;
        const float*  hp = h2s + part * 8;
        float4 w0 = w[0], w1 = w[1];
        float s = 0.f;
        s = fmaf(w0.x, hp[0], s); s = fmaf(w0.y, hp[1], s);
        s = fmaf(w0.z, hp[2], s); s = fmaf(w0.w, hp[3], s);
        s = fmaf(w1.x, hp[4], s); s = fmaf(w1.y, hp[5], s);
        s = fmaf(w1.z, hp[6], s); s = fmaf(w1.w, hp[7], s);
        pr[o * 9 + part] = s;
    }
    __syncthreads();
    if (t < NQ) {
        float s = 0.f;
        #pragma unroll
        for (int k = 0; k < 8; k++) s += pr[t * 9 + k];
        xqs[t] = tanhf(s + b3[t]);
    }
    __syncthreads();

    // ----------------- gate matrices (encoding RYs pre-merged; verified R1-R4) -----------------
    if (t < NL * NQ) {
        const int l = t / NQ;
        const int i = t % NQ;
        float a  = qw[t * 3 + 0];
        float bb = qw[t * 3 + 1];
        float c  = qw[t * 3 + 2];
        float sb, cb;   sincosf(0.5f * bb, &sb, &cb);
        float apc = 0.5f * (a + c), amc = 0.5f * (a - c);
        float sapc, capc; sincosf(apc, &sapc, &capc);
        float samc, camc; sincosf(amc, &samc, &camc);
        float u00x =  cb * capc, u00y = -cb * sapc;
        float u01x = -sb * camc, u01y = -sb * samc;
        float u10x =  sb * camc, u10y = -sb * samc;
        float u11x =  cb * capc, u11y =  cb * sapc;

        float theta = 0.f;
        bool merge = false;
        if (l == 0)      { theta = xqs[i] * PI2;        merge = true; }
        else if (l & 1)  { theta = xqs[i] * PI2 * 0.5f; merge = true; }
        if (merge) {
            float sy, cy; sincosf(0.5f * theta, &sy, &cy);
            float m00x = u00x * cy + u01x * sy, m00y = u00y * cy + u01y * sy;
            float m01x = -u00x * sy + u01x * cy, m01y = -u00y * sy + u01y * cy;
            float m10x = u10x * cy + u11x * sy, m10y = u10y * cy + u11y * sy;
            float m11x = -u10x * sy + u11x * cy, m11y = -u10y * sy + u11y * cy;
            u00x = m00x; u00y = m00y; u01x = m01x; u01y = m01y;
            u10x = m10x; u10y = m10y; u11x = m11x; u11y = m11y;
        }
        Um[t * 4 + 0] = mk2(u00x, u00y);
        Um[t * 4 + 1] = mk2(u01x, u01y);
        Um[t * 4 + 2] = mk2(u10x, u10y);
        Um[t * 4 + 3] = mk2(u11x, u11y);
    }
    __syncthreads();

    // ----------------- addressing constants -----------------
    // arrA slot i = 8t+m: bits m=i[0:2], L=i[3:8]=t[0:5], W=i[9:11]=t[6:8].
    // sigma = (0<->5)(1<->7)(2<->8)(3<->9)(4<->10)(6<->11)
    const int PwA = 8 * t + (t >> 1) + (t >> 5);     // Pad(8t): RT1 write base
    const int s0  = (((t     ) & 1) << 9) | (((t >> 1) & 1) << 10) | ((t >> 2) & 1)
                  | (((t >> 3) & 1) << 11) | (((t >> 4) & 1) << 1)  | (((t >> 5) & 1) << 2)
                  | (((t >> 6) & 1) << 3)  | (((t >> 7) & 1) << 4)  | (((t >> 8) & 1) << 6);
    const int Ps  = Pad(s0);                         // Pad(sigma(8t)): RT1 read / RT2 write base
    const int g8  = gmap(8 * t);                     // gmap is XOR-linear

    // ----------------- layer 0: product state evaluated at gmap(8t+m) -----------------
    v2f a[8];
    {
        // shared lane/wave factors: bits 3..9 of g are m-independent
        v2f common = Um[(11 - 3) * 4 + ((g8 >> 3) & 1) * 2];
        #pragma unroll
        for (int k = 4; k <= 9; k++) {
            common = cml(common, Um[(11 - k) * 4 + ((g8 >> k) & 1) * 2]);
        }
        #pragma unroll
        for (int m = 0; m < 8; m++) {
            const int gmc = (m ^ (m >> 1)) | ((m & 1) ? 0xC00 : 0);
            const int g = g8 ^ gmc;
            v2f v = common;
            v = cml(v, Um[11 * 4 + ((g     ) & 1) * 2]);
            v = cml(v, Um[10 * 4 + ((g >> 1) & 1) * 2]);
            v = cml(v, Um[ 9 * 4 + ((g >> 2) & 1) * 2]);
            v = cml(v, Um[ 1 * 4 + ((g >> 10) & 1) * 2]);
            v = cml(v, Um[ 0 * 4 + ((g >> 11) & 1) * 2]);
            a[m] = v;
        }
    }

    // ----------------- layers 1..5 -----------------
    const bool d1 = t & 1, d2 = t & 2, d8 = t & 8;
    #pragma unroll 1
    for (int l = 1; l < NL; l++) {
        const v2f* UL = &Um[l * NQ * 4];

        // arrA gates: qubits 11,10,9 (reg bits) + 8,7,5 (lane xor 1,2,8)
        gate_reg(a, &UL[11 * 4], 1);
        gate_reg(a, &UL[10 * 4], 2);
        gate_reg(a, &UL[ 9 * 4], 4);
        gate_dpp<0xB1> (a, &UL[8 * 4], d1);
        gate_dpp<0x4E> (a, &UL[7 * 4], d2);
        gate_dpp<0x128>(a, &UL[5 * 4], d8);

        // RT1: arrA -> arrB (write Pad(i), read Pad(sigma(i)))
        #pragma unroll
        for (int m = 0; m < 8; m++) bufB[PwA + m] = a[m];
        __syncthreads();
        #pragma unroll
        for (int m = 0; m < 8; m++) {
            const int dm = 34 * (m & 1) + 136 * ((m >> 1) & 1) + 273 * ((m >> 2) & 1);
            a[m] = bufB[Ps + dm];
        }

        // arrB gates: qubits 6,4,3 (reg) + 2,1,0 (lane xor 1,2,8)
        gate_reg(a, &UL[6 * 4], 1);
        gate_reg(a, &UL[4 * 4], 2);
        gate_reg(a, &UL[3 * 4], 4);
        gate_dpp<0xB1> (a, &UL[2 * 4], d1);
        gate_dpp<0x4E> (a, &UL[1 * 4], d2);
        gate_dpp<0x128>(a, &UL[0 * 4], d8);

        // RT2: arrB -> next arrA with ring fused (write Pad(sigma(i)), read Pad(gmap(i)))
        if (l < NL - 1) {
            #pragma unroll
            for (int m = 0; m < 8; m++) {
                const int dm = 34 * (m & 1) + 136 * ((m >> 1) & 1) + 273 * ((m >> 2) & 1);
                bufA[Ps + dm] = a[m];
            }
            __syncthreads();
            const bool czl = (l == 1) || (l == 3);
            #pragma unroll
            for (int m = 0; m < 8; m++) {
                const int gmc = (m ^ (m >> 1)) | ((m & 1) ? 0xC00 : 0);
                const int g = g8 ^ gmc;
                v2f v = bufA[Pad(g)];
                const int j = 8 * t + m;
                if (czl && (__popc(j & (j << 2) & 0xAA8) & 1)) v = -v;
                a[m] = v;
            }
        }
    }

    // ----------------- measurement -----------------
    // regs: arrB of layer 5, slot m holds amp[sigma(8t+m)] pre-ring5.
    // ring5 folds to parities: f11=par(j&0x7FF), f10=par(j&0xC00), f9=par(j&0xE00).
    // t-parts: p0t=par(t&0x1F7), p1t=par(t&0xA), p2t=par(t&0xB); m-part only in f11.
    float alt = 0.f, tot = 0.f;
    #pragma unroll
    for (int m = 0; m < 8; m++) {
        float p = a[m].x * a[m].x + a[m].y * a[m].y;
        tot += p;
        alt += (__popc(m) & 1) ? -p : p;
    }
    float z0 = (__popc(t & 0x1F7) & 1) ? -alt : alt;
    float z1 = (__popc(t & 0x00A) & 1) ? -tot : tot;
    float z2 = (__popc(t & 0x00B) & 1) ? -tot : tot;

    #pragma unroll
    for (int off = 32; off > 0; off >>= 1) {
        z0 += __shfl_down(z0, off);
        z1 += __shfl_down(z1, off);
        z2 += __shfl_down(z2, off);
    }
    if ((t & 63) == 0) {
        zred[t >> 6][0] = z0;
        zred[t >> 6][1] = z1;
        zred[t >> 6][2] = z2;
    }
    __syncthreads();
    if (t == 0) {
        float q0 = 0.f, q1 = 0.f, q2 = 0.f;
        #pragma unroll
        for (int w = 0; w < 8; w++) {
            q0 += zred[w][0]; q1 += zred[w][1]; q2 += zred[w][2];
        }
        qv[0] = q0; qv[1] = q1; qv[2] = q2;
    }
    __syncthreads();

    // ----------------- back-end MLP -----------------
    if (t < 32) {
        float h = b4[t];
        h = fmaf(qv[0], W4[t * 3 + 0], h);
        h = fmaf(qv[1], W4[t * 3 + 1], h);
        h = fmaf(qv[2], W4[t * 3 + 2], h);
        h4s[t] = geluf(h);
    }
    __syncthreads();
    if (t < 64) {
        float acc = b5[t];
        #pragma unroll
        for (int h = 0; h < 32; h++) acc = fmaf(h4s[h], W5[t * 32 + h], acc);
        out[b * 64 + t] = acc;
    }
}

extern "C" void kernel_launch(void* const* d_in, const int* in_sizes, int n_in,
                              void* d_out, int out_size, void* d_ws, size_t ws_size,
                              hipStream_t stream) {
    (void)in_sizes; (void)n_in; (void)d_ws; (void)ws_size; (void)out_size;
    const float* x    = (const float*)d_in[0];
    const float* W1   = (const float*)d_in[1];
    const float* b1   = (const float*)d_in[2];
    const float* g_ln = (const float*)d_in[3];
    const float* b_ln = (const float*)d_in[4];
    const float* W2   = (const float*)d_in[5];
    const float* b2   = (const float*)d_in[6];
    const float* W3   = (const float*)d_in[7];
    const float* b3   = (const float*)d_in[8];
    const float* qw   = (const float*)d_in[9];
    const float* W4   = (const float*)d_in[10];
    const float* b4   = (const float*)d_in[11];
    const float* W5   = (const float*)d_in[12];
    const float* b5   = (const float*)d_in[13];
    float* out = (float*)d_out;

    qpu_kernel<<<BATCH, NT, 0, stream>>>(x, W1, b1, g_ln, b_ln, W2, b2,
                                         W3, b3, qw, W4, b4, W5, b5, out);
}

// Round 6
// 103.106 us; speedup vs baseline: 1.0506x; 1.0506x over previous
//
#include <hip/hip_runtime.h>
#include <math.h>

#define NQ   12
#define NL   6
#define BATCH 256
#define NT   1024      // 16 waves/CU = 4 waves/SIMD (best measured: K3)
#define PI2  9.869604401089358f   // pi*pi

typedef float v2f __attribute__((ext_vector_type(2)));

__device__ __forceinline__ float geluf(float x) {
    return 0.5f * x * (1.0f + erff(x * 0.70710678118654752f));
}

// LDS pad (float2 units): P(x) = x + (x>>4) + (x>>8)
__device__ __forceinline__ int Pad(int x) { return x + (x >> 4) + (x >> 8); }

// ring-CNOT gather map (GF(2)-linear; HW-verified R1-R4)
__device__ __forceinline__ int gmap(int j) {
    return ((j ^ (j >> 1)) & 0x3FF)
         | ((((j >> 10) ^ (j >> 11) ^ j) & 1) << 10)
         | ((((j >> 11) ^ j) & 1) << 11);
}

// DPP lane-xor on one v2f (2 VGPRs): xor1=0xB1, xor2=0x4E, xor8=row_ror:8=0x128
template<int CTRL>
__device__ __forceinline__ v2f dppv(v2f v) {
    int x = __builtin_amdgcn_update_dpp(0, __float_as_int(v.x), CTRL, 0xF, 0xF, true);
    int y = __builtin_amdgcn_update_dpp(0, __float_as_int(v.y), CTRL, 0xF, 0xF, true);
    v2f r; r.x = __int_as_float(x); r.y = __int_as_float(y); return r;
}
// ds_swizzle lane-xor4 (BitMode 0x101F; HW-verified K3)
__device__ __forceinline__ v2f swz4(v2f v) {
    int x = __builtin_amdgcn_ds_swizzle(__float_as_int(v.x), 0x101F);
    int y = __builtin_amdgcn_ds_swizzle(__float_as_int(v.y), 0x101F);
    v2f r; r.x = __int_as_float(x); r.y = __int_as_float(y); return r;
}

__global__ __launch_bounds__(NT)
void qpu_kernel(const float* __restrict__ x,   const float* __restrict__ W1, const float* __restrict__ b1,
                const float* __restrict__ g_ln, const float* __restrict__ b_ln,
                const float* __restrict__ W2,  const float* __restrict__ b2,
                const float* __restrict__ W3,  const float* __restrict__ b3,
                const float* __restrict__ qw,  const float* __restrict__ W4, const float* __restrict__ b4,
                const float* __restrict__ W5,  const float* __restrict__ b5,
                float* __restrict__ out)
{
    __shared__ float2 bufA[4368];      // ring-RT buffer (Pad(4095)=4365)
    __shared__ float2 bufB[4368];      // sigma-RT buffer
    __shared__ float  Um8[NL * NQ * 8];// per gate: u00x,u00y,u01x,u01y,u10x,u10y,u11x,u11y
    __shared__ float  xs[256];
    __shared__ float  pr[1280];
    __shared__ float  h1n[128];
    __shared__ float  h2s[64];
    __shared__ float  xqs[NQ];
    __shared__ float  musd[2];
    __shared__ float  qv[3];
    __shared__ float  h4s[32];
    __shared__ float  zred[16][3];

    const int t = threadIdx.x;
    const int b = blockIdx.x;

    // ----------------- front-end MLP (split-K, all 1024 threads) -----------------
    if (t < 256) xs[t] = x[b * 256 + t];
    __syncthreads();

    // h1: 128 outs x 8 parts x 32 elems
    {
        const int o = t >> 3, part = t & 7;
        const float4* w  = (const float4*)(W1 + o * 256) + part * 8;
        const float*  xp = xs + part * 32;
        float a0 = 0.f, a1 = 0.f, a2 = 0.f, a3 = 0.f;
        #pragma unroll
        for (int k = 0; k < 8; k++) {
            float4 wv = w[k];
            a0 = fmaf(wv.x, xp[4 * k + 0], a0);
            a1 = fmaf(wv.y, xp[4 * k + 1], a1);
            a2 = fmaf(wv.z, xp[4 * k + 2], a2);
            a3 = fmaf(wv.w, xp[4 * k + 3], a3);
        }
        pr[o * 9 + part] = (a0 + a1) + (a2 + a3);
    }
    __syncthreads();
    if (t < 128) {
        float s = 0.f;
        #pragma unroll
        for (int k = 0; k < 8; k++) s += pr[t * 9 + k];
        h1n[t] = geluf(s + b1[t]);
    }
    __syncthreads();

    if (t < 64) {
        float v0 = h1n[t], v1 = h1n[t + 64];
        float s1 = v0 + v1;
        float s2 = fmaf(v0, v0, v1 * v1);
        #pragma unroll
        for (int off = 32; off > 0; off >>= 1) {
            s1 += __shfl_down(s1, off);
            s2 += __shfl_down(s2, off);
        }
        if (t == 0) {
            float mu  = s1 * (1.f / 128.f);
            float var = s2 * (1.f / 128.f) - mu * mu;
            musd[0] = mu;
            musd[1] = rsqrtf(var + 1e-5f);
        }
    }
    __syncthreads();
    if (t < 128) h1n[t] = (h1n[t] - musd[0]) * musd[1] * g_ln[t] + b_ln[t];
    __syncthreads();

    // h2: 64 outs x 8 parts x 16 elems
    if (t < 512) {
        const int o = t >> 3, part = t & 7;
        const float4* w  = (const float4*)(W2 + o * 128) + part * 4;
        const float*  hp = h1n + part * 16;
        float a0 = 0.f, a1 = 0.f, a2 = 0.f, a3 = 0.f;
        #pragma unroll
        for (int k = 0; k < 4; k++) {
            float4 wv = w[k];
            a0 = fmaf(wv.x, hp[4 * k + 0], a0);
            a1 = fmaf(wv.y, hp[4 * k + 1], a1);
            a2 = fmaf(wv.z, hp[4 * k + 2], a2);
            a3 = fmaf(wv.w, hp[4 * k + 3], a3);
        }
        pr[o * 9 + part] = (a0 + a1) + (a2 + a3);
    }
    __syncthreads();
    if (t < 64) {
        float s = 0.f;
        #pragma unroll
        for (int k = 0; k < 8; k++) s += pr[t * 9 + k];
        h2s[t] = geluf(s + b2[t]);
    }
    __syncthreads();

    // xq: 12 outs x 8 parts x 8 elems
    if (t < 96) {
        const int o = t >> 3, part = t & 7;
        const float4* w  = (const float4*)(W3 + o * 64) + part * 2;
        const float*  hp = h2s + part * 8;
        float4 w0 = w[0], w1 = w[1];
        float s = 0.f;
        s = fmaf(w0.x, hp[0], s); s = fmaf(w0.y, hp[1], s);
        s = fmaf(w0.z, hp[2], s); s = fmaf(w0.w, hp[3], s);
        s = fmaf(w1.x, hp[4], s); s = fmaf(w1.y, hp[5], s);
        s = fmaf(w1.z, hp[6], s); s = fmaf(w1.w, hp[7], s);
        pr[o * 9 + part] = s;
    }
    __syncthreads();
    if (t < NQ) {
        float s = 0.f;
        #pragma unroll
        for (int k = 0; k < 8; k++) s += pr[t * 9 + k];
        xqs[t] = tanhf(s + b3[t]);
    }
    __syncthreads();

    // ----------------- gate matrices (encoding RYs pre-merged; verified R1-R4) -----------------
    if (t < NL * NQ) {
        const int l = t / NQ;
        const int i = t % NQ;
        float a  = qw[t * 3 + 0];
        float bb = qw[t * 3 + 1];
        float c  = qw[t * 3 + 2];
        float sb, cb;   sincosf(0.5f * bb, &sb, &cb);
        float apc = 0.5f * (a + c), amc = 0.5f * (a - c);
        float sapc, capc; sincosf(apc, &sapc, &capc);
        float samc, camc; sincosf(amc, &samc, &camc);
        float u00x =  cb * capc, u00y = -cb * sapc;
        float u01x = -sb * camc, u01y = -sb * samc;
        float u10x =  sb * camc, u10y = -sb * samc;
        float u11x =  cb * capc, u11y =  cb * sapc;

        float theta = 0.f;
        bool merge = false;
        if (l == 0)      { theta = xqs[i] * PI2;        merge = true; }
        else if (l & 1)  { theta = xqs[i] * PI2 * 0.5f; merge = true; }
        if (merge) {
            float sy, cy; sincosf(0.5f * theta, &sy, &cy);
            float m00x = u00x * cy + u01x * sy,  m00y = u00y * cy + u01y * sy;
            float m01x = -u00x * sy + u01x * cy, m01y = -u00y * sy + u01y * cy;
            float m10x = u10x * cy + u11x * sy,  m10y = u10y * cy + u11y * sy;
            float m11x = -u10x * sy + u11x * cy, m11y = -u10y * sy + u11y * cy;
            u00x = m00x; u00y = m00y; u01x = m01x; u01y = m01y;
            u10x = m10x; u10y = m10y; u11x = m11x; u11y = m11y;
        }
        float* d = &Um8[t * 8];
        d[0] = u00x; d[1] = u00y; d[2] = u01x; d[3] = u01y;
        d[4] = u10x; d[5] = u10y; d[6] = u11x; d[7] = u11y;
    }
    __syncthreads();

    // ----------------- addressing constants -----------------
    // j = 4t+m: bits 0,1 = m; 2..7 = lane (t0..t5); 8..11 = wave (t6..t9).
    // sigma = block swap j0..5 <-> j6..11.
    const int PwA = 4 * t + (t >> 2) + (t >> 6);                 // Pad(4t)
    const int s0  = ((t >> 4) & 3) | (((t >> 6) & 15) << 2) | ((t & 15) << 8);
    const int Ps  = Pad(s0);                                     // Pad(sigma(4t)); +68m for m
    const int g4t = gmap(4 * t);
    const int pg0 = Pad(g4t);                                    // Pad(gmap(4t+m)), m=0..3
    const int pg1 = Pad(g4t ^ 0xC01);
    const int pg2 = Pad(g4t ^ 0x003);
    const int pg3 = Pad(g4t ^ 0xC02);
    // CZ sign (layers 1,3): base parity of {t1t3,t3t5,t5t7,t7t9}; m>=2 adds t1
    const int  czb = __popc(t & (t >> 2) & 0xAA) & 1;
    const float sA = czb ? -1.f : 1.f;
    const float sB = (czb ^ ((t >> 1) & 1)) ? -1.f : 1.f;
    const bool d1 = t & 1, d2 = t & 2, d4 = t & 4, d8 = t & 8;

    // ----------------- layer 0: product state at gmap(4t+m) (ring-0 folded) -----------------
    // SoA state: R01=(re_m0,re_m1), R23=(re_m2,re_m3); I01, I23 imag.
    v2f R01, R23, I01, I23;
    {
        // common factors: g bits 2..9 (m-independent), qubit = 11-bit
        float cr, ci;
        {
            const float* u = &Um8[9 * 8 + (((g4t >> 2) & 1) << 2)];
            cr = u[0]; ci = u[1];
        }
        #pragma unroll
        for (int k = 3; k <= 9; k++) {
            const float* u = &Um8[(11 - k) * 8 + (((g4t >> k) & 1) << 2)];
            float nr = cr * u[0] - ci * u[1];
            float ni = cr * u[1] + ci * u[0];
            cr = nr; ci = ni;
        }
        const int GM[4] = {0, 0xC01, 0x003, 0xC02};
        float vr[4], vi[4];
        #pragma unroll
        for (int m = 0; m < 4; m++) {
            const int g = g4t ^ GM[m];
            float rr = cr, ii = ci;
            const float* u0 = &Um8[11 * 8 + ((g & 1) << 2)];
            const float* u1 = &Um8[10 * 8 + (((g >> 1) & 1) << 2)];
            const float* ua = &Um8[ 1 * 8 + (((g >> 10) & 1) << 2)];
            const float* ub = &Um8[ 0 * 8 + (((g >> 11) & 1) << 2)];
            float nr, ni;
            nr = rr * u0[0] - ii * u0[1]; ni = rr * u0[1] + ii * u0[0]; rr = nr; ii = ni;
            nr = rr * u1[0] - ii * u1[1]; ni = rr * u1[1] + ii * u1[0]; rr = nr; ii = ni;
            nr = rr * ua[0] - ii * ua[1]; ni = rr * ua[1] + ii * ua[0]; rr = nr; ii = ni;
            nr = rr * ub[0] - ii * ub[1]; ni = rr * ub[1] + ii * ub[0]; rr = nr; ii = ni;
            vr[m] = rr; vi[m] = ii;
        }
        R01.x = vr[0]; R01.y = vr[1]; R23.x = vr[2]; R23.y = vr[3];
        I01.x = vi[0]; I01.y = vi[1]; I23.x = vi[2]; I23.y = vi[3];
    }

    // ----------------- layers 1..5 -----------------
    #pragma unroll 1
    for (int l = 1; l < NL; l++) {
        const float* UL = &Um8[l * NQ * 8];

        // ===== arrangement A: j0..j5 = qubits 11..6 =====
        // q11 (j0, within-pack): scalar butterflies on (.x,.y) of each pack
        {
            const float* u = &UL[11 * 8];
            float r0 = R01.x, i0 = I01.x, r1 = R01.y, i1 = I01.y;
            R01.x = u[0]*r0 - u[1]*i0 + u[2]*r1 - u[3]*i1;
            I01.x = u[0]*i0 + u[1]*r0 + u[2]*i1 + u[3]*r1;
            R01.y = u[4]*r0 - u[5]*i0 + u[6]*r1 - u[7]*i1;
            I01.y = u[4]*i0 + u[5]*r0 + u[6]*i1 + u[7]*r1;
            r0 = R23.x; i0 = I23.x; r1 = R23.y; i1 = I23.y;
            R23.x = u[0]*r0 - u[1]*i0 + u[2]*r1 - u[3]*i1;
            I23.x = u[0]*i0 + u[1]*r0 + u[2]*i1 + u[3]*r1;
            R23.y = u[4]*r0 - u[5]*i0 + u[6]*r1 - u[7]*i1;
            I23.y = u[4]*i0 + u[5]*r0 + u[6]*i1 + u[7]*r1;
        }
        // q10 (j1, cross-pack): packed butterfly
        {
            const float* u = &UL[10 * 8];
            v2f r0 = u[0]*R01 - u[1]*I01 + u[2]*R23 - u[3]*I23;
            v2f i0 = u[0]*I01 + u[1]*R01 + u[2]*I23 + u[3]*R23;
            v2f r1 = u[4]*R01 - u[5]*I01 + u[6]*R23 - u[7]*I23;
            v2f i1 = u[4]*I01 + u[5]*R01 + u[6]*I23 + u[7]*R23;
            R01 = r0; I01 = i0; R23 = r1; I23 = i1;
        }
        // lane gates (packed combine with permuted partner)
        #define LANE_GATE(PERM, Q, SEL) do {                                  \
            const float* u = &UL[(Q) * 8];                                    \
            float cAx = (SEL) ? u[6] : u[0], cAy = (SEL) ? u[7] : u[1];       \
            float cBx = (SEL) ? u[4] : u[2], cBy = (SEL) ? u[5] : u[3];       \
            v2f vR0 = PERM(R01), vI0 = PERM(I01);                             \
            v2f vR1 = PERM(R23), vI1 = PERM(I23);                             \
            v2f nR0 = cAx*R01 - cAy*I01 + cBx*vR0 - cBy*vI0;                  \
            v2f nI0 = cAx*I01 + cAy*R01 + cBx*vI0 + cBy*vR0;                  \
            v2f nR1 = cAx*R23 - cAy*I23 + cBx*vR1 - cBy*vI1;                  \
            v2f nI1 = cAx*I23 + cAy*R23 + cBx*vI1 + cBy*vR1;                  \
            R01 = nR0; I01 = nI0; R23 = nR1; I23 = nI1; } while (0)

        LANE_GATE(dppv<0xB1>,  9, d1);   // j2: lane xor1
        LANE_GATE(dppv<0x4E>,  8, d2);   // j3: lane xor2
        LANE_GATE(swz4,        7, d4);   // j4: lane xor4
        LANE_GATE(dppv<0x128>, 6, d8);   // j5: lane xor8

        // RT1: write amp[4t+m] at Pad(4t)+m, read amp[sigma(4t+m)] at Ps+68m
        bufB[PwA + 0] = make_float2(R01.x, I01.x);
        bufB[PwA + 1] = make_float2(R01.y, I01.y);
        bufB[PwA + 2] = make_float2(R23.x, I23.x);
        bufB[PwA + 3] = make_float2(R23.y, I23.y);
        __syncthreads();
        {
            float2 v0 = bufB[Ps], v1 = bufB[Ps + 68], v2 = bufB[Ps + 136], v3 = bufB[Ps + 204];
            R01.x = v0.x; I01.x = v0.y; R01.y = v1.x; I01.y = v1.y;
            R23.x = v2.x; I23.x = v2.y; R23.y = v3.x; I23.y = v3.y;
        }

        // ===== arrangement B: j6..j11 = qubits 5..0 =====
        {
            const float* u = &UL[5 * 8];     // q5 (s-bit0, within-pack)
            float r0 = R01.x, i0 = I01.x, r1 = R01.y, i1 = I01.y;
            R01.x = u[0]*r0 - u[1]*i0 + u[2]*r1 - u[3]*i1;
            I01.x = u[0]*i0 + u[1]*r0 + u[2]*i1 + u[3]*r1;
            R01.y = u[4]*r0 - u[5]*i0 + u[6]*r1 - u[7]*i1;
            I01.y = u[4]*i0 + u[5]*r0 + u[6]*i1 + u[7]*r1;
            r0 = R23.x; i0 = I23.x; r1 = R23.y; i1 = I23.y;
            R23.x = u[0]*r0 - u[1]*i0 + u[2]*r1 - u[3]*i1;
            I23.x = u[0]*i0 + u[1]*r0 + u[2]*i1 + u[3]*r1;
            R23.y = u[4]*r0 - u[5]*i0 + u[6]*r1 - u[7]*i1;
            I23.y = u[4]*i0 + u[5]*r0 + u[6]*i1 + u[7]*r1;
        }
        {
            const float* u = &UL[4 * 8];     // q4 (s-bit1, cross-pack)
            v2f r0 = u[0]*R01 - u[1]*I01 + u[2]*R23 - u[3]*I23;
            v2f i0 = u[0]*I01 + u[1]*R01 + u[2]*I23 + u[3]*R23;
            v2f r1 = u[4]*R01 - u[5]*I01 + u[6]*R23 - u[7]*I23;
            v2f i1 = u[4]*I01 + u[5]*R01 + u[6]*I23 + u[7]*R23;
            R01 = r0; I01 = i0; R23 = r1; I23 = i1;
        }
        LANE_GATE(dppv<0xB1>,  3, d1);   // q3: lane xor1
        LANE_GATE(dppv<0x4E>,  2, d2);   // q2: lane xor2
        LANE_GATE(swz4,        1, d4);   // q1: lane xor4
        LANE_GATE(dppv<0x128>, 0, d8);   // q0: lane xor8
        #undef LANE_GATE

        // RT2: write amp[sigma(4t+m)] at Ps+68m, read amp[gmap(4t+m)] (+CZ l=1,3)
        if (l < NL - 1) {
            bufA[Ps +   0] = make_float2(R01.x, I01.x);
            bufA[Ps +  68] = make_float2(R01.y, I01.y);
            bufA[Ps + 136] = make_float2(R23.x, I23.x);
            bufA[Ps + 204] = make_float2(R23.y, I23.y);
            __syncthreads();
            float2 w0 = bufA[pg0], w1 = bufA[pg1], w2 = bufA[pg2], w3 = bufA[pg3];
            if ((l == 1) || (l == 3)) {
                w0.x *= sA; w0.y *= sA; w1.x *= sA; w1.y *= sA;
                w2.x *= sB; w2.y *= sB; w3.x *= sB; w3.y *= sB;
            }
            R01.x = w0.x; I01.x = w0.y; R01.y = w1.x; I01.y = w1.y;
            R23.x = w2.x; I23.x = w2.y; R23.y = w3.x; I23.y = w3.y;
        }
    }

    // ----------------- measurement -----------------
    // regs: arrB of layer 5, slot m holds amp[sigma(4t+m)] pre-ring5.
    // ring5 folds to parities: z0 sign = par(t&0x3F7)^par(m); z1: par(t&0xC); z2: par(t&0xE).
    float p0 = R01.x * R01.x + I01.x * I01.x;
    float p1 = R01.y * R01.y + I01.y * I01.y;
    float p2 = R23.x * R23.x + I23.x * I23.x;
    float p3 = R23.y * R23.y + I23.y * I23.y;
    float alt = (p0 - p1) - (p2 - p3);
    float tot = (p0 + p1) + (p2 + p3);
    float z0 = (__popc(t & 0x3F7) & 1) ? -alt : alt;
    float z1 = (__popc(t & 0x00C) & 1) ? -tot : tot;
    float z2 = (__popc(t & 0x00E) & 1) ? -tot : tot;

    #pragma unroll
    for (int off = 32; off > 0; off >>= 1) {
        z0 += __shfl_down(z0, off);
        z1 += __shfl_down(z1, off);
        z2 += __shfl_down(z2, off);
    }
    if ((t & 63) == 0) {
        zred[t >> 6][0] = z0;
        zred[t >> 6][1] = z1;
        zred[t >> 6][2] = z2;
    }
    __syncthreads();
    if (t == 0) {
        float q0 = 0.f, q1 = 0.f, q2 = 0.f;
        #pragma unroll
        for (int w = 0; w < 16; w++) {
            q0 += zred[w][0]; q1 += zred[w][1]; q2 += zred[w][2];
        }
        qv[0] = q0; qv[1] = q1; qv[2] = q2;
    }
    __syncthreads();

    // ----------------- back-end MLP -----------------
    if (t < 32) {
        float h = b4[t];
        h = fmaf(qv[0], W4[t * 3 + 0], h);
        h = fmaf(qv[1], W4[t * 3 + 1], h);
        h = fmaf(qv[2], W4[t * 3 + 2], h);
        h4s[t] = geluf(h);
    }
    __syncthreads();
    if (t < 64) {
        float acc = b5[t];
        #pragma unroll
        for (int h = 0; h < 32; h++) acc = fmaf(h4s[h], W5[t * 32 + h], acc);
        out[b * 64 + t] = acc;
    }
}

extern "C" void kernel_launch(void* const* d_in, const int* in_sizes, int n_in,
                              void* d_out, int out_size, void* d_ws, size_t ws_size,
                              hipStream_t stream) {
    (void)in_sizes; (void)n_in; (void)d_ws; (void)ws_size; (void)out_size;
    const float* x    = (const float*)d_in[0];
    const float* W1   = (const float*)d_in[1];
    const float* b1   = (const float*)d_in[2];
    const float* g_ln = (const float*)d_in[3];
    const float* b_ln = (const float*)d_in[4];
    const float* W2   = (const float*)d_in[5];
    const float* b2   = (const float*)d_in[6];
    const float* W3   = (const float*)d_in[7];
    const float* b3   = (const float*)d_in[8];
    const float* qw   = (const float*)d_in[9];
    const float* W4   = (const float*)d_in[10];
    const float* b4   = (const float*)d_in[11];
    const float* W5   = (const float*)d_in[12];
    const float* b5   = (const float*)d_in[13];
    float* out = (float*)d_out;

    qpu_kernel<<<BATCH, NT, 0, stream>>>(x, W1, b1, g_ln, b_ln, W2, b2,
                                         W3, b3, qw, W4, b4, W5, b5, out);
}

// Round 7
// 103.029 us; speedup vs baseline: 1.0514x; 1.0007x over previous
//
#include <hip/hip_runtime.h>
#include <math.h>

#define NQ   12
#define NL   6
#define BATCH 256
#define NT   512       // 8 waves/CU: halves per-CU LDS issue vs 1024
#define PI2  9.869604401089358f   // pi*pi

typedef float v2f __attribute__((ext_vector_type(2)));

__device__ __forceinline__ float geluf(float x) {
    return 0.5f * x * (1.0f + erff(x * 0.70710678118654752f));
}

// LDS pad (float2 units): P(x) = x + (x>>4) + (x>>8); additive over disjoint bits.
__device__ __forceinline__ int Pad(int x) { return x + (x >> 4) + (x >> 8); }

// ring-CNOT gather map (GF(2)-linear; HW-verified R1-R5)
__device__ __forceinline__ int gmap(int j) {
    return ((j ^ (j >> 1)) & 0x3FF)
         | ((((j >> 10) ^ (j >> 11) ^ j) & 1) << 10)
         | ((((j >> 11) ^ j) & 1) << 11);
}

// sigma: bit swaps 0<->5, 1<->7, 2<->8, 3<->9, 4<->10, 6<->11 (involution)
__device__ __forceinline__ int sigma(int x) {
    return ((x & 0x1E) << 6) | ((x & 0x780) >> 6)
         | ((x & 0x41) << 5) | ((x & 0x820) >> 5);
}

// DPP lane-xor: xor1 = quad_perm 0xB1, xor2 = 0x4E, xor8 = row_ror:8 = 0x128 (HW-verified)
template<int CTRL>
__device__ __forceinline__ v2f dppv(v2f v) {
    int x = __builtin_amdgcn_update_dpp(0, __float_as_int(v.x), CTRL, 0xF, 0xF, true);
    int y = __builtin_amdgcn_update_dpp(0, __float_as_int(v.y), CTRL, 0xF, 0xF, true);
    v2f r; r.x = __int_as_float(x); r.y = __int_as_float(y); return r;
}

__global__ __launch_bounds__(NT)
void qpu_kernel(const float* __restrict__ x,   const float* __restrict__ W1, const float* __restrict__ b1,
                const float* __restrict__ g_ln, const float* __restrict__ b_ln,
                const float* __restrict__ W2,  const float* __restrict__ b2,
                const float* __restrict__ W3,  const float* __restrict__ b3,
                const float* __restrict__ qw,  const float* __restrict__ W4, const float* __restrict__ b4,
                const float* __restrict__ W5,  const float* __restrict__ b5,
                float* __restrict__ out)
{
    __shared__ float2 bufA[4368];       // arrA state (RT1)
    __shared__ float2 bufB[4368];       // arrB state (RT2)
    __shared__ float  Umr[5 * 12 * 8];  // layers 1..5, role-ordered coefficients
    __shared__ float4 L0c[12];          // layer-0 col0: (u00x,u00y,u10x,u10y)
    __shared__ float  xs[256];
    __shared__ float  pr[1280];
    __shared__ float  h1n[128];
    __shared__ float  h2s[64];
    __shared__ float  xqs[NQ];
    __shared__ float  musd[2];
    __shared__ float  qv[3];
    __shared__ float  h4s[32];
    __shared__ float  zred[8][3];

    const int t = threadIdx.x;
    const int b = blockIdx.x;

    // ----------------- front-end MLP (split-K) -----------------
    if (t < 256) xs[t] = x[b * 256 + t];
    __syncthreads();

    // h1: 128 outs x 4 parts x 64 elems
    {
        const int o = t >> 2, part = t & 3;
        const float4* w  = (const float4*)(W1 + o * 256) + part * 16;
        const float*  xp = xs + part * 64;
        float a0 = 0.f, a1 = 0.f, a2 = 0.f, a3 = 0.f;
        #pragma unroll
        for (int k = 0; k < 16; k++) {
            float4 wv = w[k];
            a0 = fmaf(wv.x, xp[4 * k + 0], a0);
            a1 = fmaf(wv.y, xp[4 * k + 1], a1);
            a2 = fmaf(wv.z, xp[4 * k + 2], a2);
            a3 = fmaf(wv.w, xp[4 * k + 3], a3);
        }
        pr[o * 5 + part] = (a0 + a1) + (a2 + a3);
    }
    __syncthreads();
    if (t < 128) {
        float s = pr[t * 5 + 0] + pr[t * 5 + 1] + pr[t * 5 + 2] + pr[t * 5 + 3];
        h1n[t] = geluf(s + b1[t]);
    }
    __syncthreads();

    if (t < 64) {
        float v0 = h1n[t], v1 = h1n[t + 64];
        float s1 = v0 + v1;
        float s2 = fmaf(v0, v0, v1 * v1);
        #pragma unroll
        for (int off = 32; off > 0; off >>= 1) {
            s1 += __shfl_down(s1, off);
            s2 += __shfl_down(s2, off);
        }
        if (t == 0) {
            float mu  = s1 * (1.f / 128.f);
            float var = s2 * (1.f / 128.f) - mu * mu;
            musd[0] = mu;
            musd[1] = rsqrtf(var + 1e-5f);
        }
    }
    __syncthreads();
    if (t < 128) h1n[t] = (h1n[t] - musd[0]) * musd[1] * g_ln[t] + b_ln[t];
    __syncthreads();

    // h2: 64 outs x 8 parts x 16 elems (all 512 threads)
    {
        const int o = t >> 3, part = t & 7;
        const float4* w  = (const float4*)(W2 + o * 128) + part * 4;
        const float*  hp = h1n + part * 16;
        float a0 = 0.f, a1 = 0.f, a2 = 0.f, a3 = 0.f;
        #pragma unroll
        for (int k = 0; k < 4; k++) {
            float4 wv = w[k];
            a0 = fmaf(wv.x, hp[4 * k + 0], a0);
            a1 = fmaf(wv.y, hp[4 * k + 1], a1);
            a2 = fmaf(wv.z, hp[4 * k + 2], a2);
            a3 = fmaf(wv.w, hp[4 * k + 3], a3);
        }
        pr[o * 9 + part] = (a0 + a1) + (a2 + a3);
    }
    __syncthreads();
    if (t < 64) {
        float s = 0.f;
        #pragma unroll
        for (int k = 0; k < 8; k++) s += pr[t * 9 + k];
        h2s[t] = geluf(s + b2[t]);
    }
    __syncthreads();

    // xq: 12 outs x 8 parts x 8 elems
    if (t < 96) {
        const int o = t >> 3, part = t & 7;
        const float4* w  = (const float4*)(W3 + o * 64) + part * 2;
        const float*  hp = h2s + part * 8;
        float4 w0 = w[0], w1 = w[1];
        float s = 0.f;
        s = fmaf(w0.x, hp[0], s); s = fmaf(w0.y, hp[1], s);
        s = fmaf(w0.z, hp[2], s); s = fmaf(w0.w, hp[3], s);
        s = fmaf(w1.x, hp[4], s); s = fmaf(w1.y, hp[5], s);
        s = fmaf(w1.z, hp[6], s); s = fmaf(w1.w, hp[7], s);
        pr[o * 9 + part] = s;
    }
    __syncthreads();
    if (t < NQ) {
        float s = 0.f;
        #pragma unroll
        for (int k = 0; k < 8; k++) s += pr[t * 9 + k];
        xqs[t] = tanhf(s + b3[t]);
    }
    __syncthreads();

    // ----------------- gate matrices: role-ordered stores -----------------
    // Roles per layer: in-pack {11,6}; cross-pack {10,9,4,3}; DPP {8,7,5,2,1,0}.
    if (t < NL * NQ) {
        const int l = t / NQ;
        const int i = t % NQ;
        float a  = qw[t * 3 + 0];
        float bb = qw[t * 3 + 1];
        float c  = qw[t * 3 + 2];
        float sb, cb;   sincosf(0.5f * bb, &sb, &cb);
        float apc = 0.5f * (a + c), amc = 0.5f * (a - c);
        float sapc, capc; sincosf(apc, &sapc, &capc);
        float samc, camc; sincosf(amc, &samc, &camc);
        float u00x =  cb * capc, u00y = -cb * sapc;
        float u01x = -sb * camc, u01y = -sb * samc;
        float u10x =  sb * camc, u10y = -sb * samc;
        float u11x =  cb * capc, u11y =  cb * sapc;

        float theta = 0.f;
        bool merge = false;
        if (l == 0)      { theta = xqs[i] * PI2;        merge = true; }
        else if (l & 1)  { theta = xqs[i] * PI2 * 0.5f; merge = true; }
        if (merge) {
            float sy, cy; sincosf(0.5f * theta, &sy, &cy);
            float m00x = u00x * cy + u01x * sy,  m00y = u00y * cy + u01y * sy;
            float m01x = -u00x * sy + u01x * cy, m01y = -u00y * sy + u01y * cy;
            float m10x = u10x * cy + u11x * sy,  m10y = u10y * cy + u11y * sy;
            float m11x = -u10x * sy + u11x * cy, m11y = -u10y * sy + u11y * cy;
            u00x = m00x; u00y = m00y; u01x = m01x; u01y = m01y;
            u10x = m10x; u10y = m10y; u11x = m11x; u11y = m11y;
        }
        if (l == 0) {
            L0c[i] = make_float4(u00x, u00y, u10x, u10y);
        } else {
            float* d = &Umr[((l - 1) * 12 + i) * 8];
            if (i == 11 || i == 6) {
                // in-pack, transposed: (CAr0,CAr1,CAi0,CAi1) (CBr0,CBr1,CBi0,CBi1)
                d[0] = u00x; d[1] = u10x; d[2] = u00y; d[3] = u10y;
                d[4] = u01x; d[5] = u11x; d[6] = u01y; d[7] = u11y;
            } else if (i == 10 || i == 9 || i == 4 || i == 3) {
                // cross-pack, plain rows
                d[0] = u00x; d[1] = u00y; d[2] = u01x; d[3] = u01y;
                d[4] = u10x; d[5] = u10y; d[6] = u11x; d[7] = u11y;
            } else {
                // DPP, sel-indexed: sel=0 -> (u00,u01); sel=1 -> (u11,u10)
                d[0] = u00x; d[1] = u00y; d[2] = u01x; d[3] = u01y;
                d[4] = u11x; d[5] = u11y; d[6] = u10x; d[7] = u10y;
            }
        }
    }
    __syncthreads();

    // ----------------- addressing constants (all loop-invariant) -----------------
    // storage j = 8t+m (arrA = phys): m bits 0-2 (pack), lane t0-5 = bits 3-8, wave t6-8 = bits 9-11.
    const int PwA = 8 * t + (t >> 1) + (t >> 5);   // Pad(8t); +m contiguous
    const int s8t = sigma(8 * t);
    const int Ps  = Pad(s8t);                      // sigma(m) deltas: bit5->34, bit7->136, bit8->273
    const int SD[8] = {0, 34, 136, 170, 273, 307, 409, 443};
    const int g8t = gmap(8 * t);
    const int GMm[8] = {0, 0xC01, 3, 0xC02, 6, 0xC07, 5, 0xC04};
    int   qm[8];
    float czm[8];
    #pragma unroll
    for (int m = 0; m < 8; m++) {
        qm[m] = Pad(g8t ^ GMm[m]);
        const int j = 8 * t + m;
        czm[m] = (__popc(j & (j << 2) & 0xAA8) & 1) ? -1.f : 1.f;
    }
    const bool t0 = t & 1, t1 = t & 2, t3 = t & 8;

    // ----------------- layer 0: product state at gmap(8t+m) (ring-0 folded) -----------------
    v2f R[4], I[4];
    {
        // common: phys bits 3..9 (qubits 8..2), m-independent
        float cr, ci;
        {
            const float4 f = L0c[8];
            const bool bit = (g8t >> 3) & 1;
            cr = bit ? f.z : f.x; ci = bit ? f.w : f.y;
        }
        #pragma unroll
        for (int k = 4; k <= 9; k++) {
            const float4 f = L0c[11 - k];
            const bool bit = (g8t >> k) & 1;
            const float fr = bit ? f.z : f.x, fi = bit ? f.w : f.y;
            const float nr = cr * fr - ci * fi;
            const float ni = cr * fi + ci * fr;
            cr = nr; ci = ni;
        }
        #pragma unroll
        for (int m = 0; m < 8; m++) {
            const int g = g8t ^ GMm[m];
            float rr = cr, ii = ci;
            const int KB[5] = {0, 1, 2, 10, 11};
            #pragma unroll
            for (int q = 0; q < 5; q++) {
                const int k = KB[q];
                const float4 f = L0c[11 - k];
                const bool bit = (g >> k) & 1;
                const float fr = bit ? f.z : f.x, fi = bit ? f.w : f.y;
                const float nr = rr * fr - ii * fi;
                const float ni = rr * fi + ii * fr;
                rr = nr; ii = ni;
            }
            if (m & 1) { R[m >> 1].y = rr; I[m >> 1].y = ii; }
            else       { R[m >> 1].x = rr; I[m >> 1].x = ii; }
        }
    }

    // ----------------- gate macros -----------------
    #define GATE_IP(BASE) do {                                                \
        const float4 A  = *(const float4*)(BASE);                             \
        const float4 Bq = *(const float4*)((BASE) + 4);                       \
        v2f CAr, CAi, CBr, CBi;                                               \
        CAr.x = A.x;  CAr.y = A.y;  CAi.x = A.z;  CAi.y = A.w;                \
        CBr.x = Bq.x; CBr.y = Bq.y; CBi.x = Bq.z; CBi.y = Bq.w;               \
        _Pragma("unroll")                                                     \
        for (int k = 0; k < 4; k++) {                                         \
            v2f rxx, ryy, ixx, iyy;                                           \
            rxx.x = R[k].x; rxx.y = R[k].x; ryy.x = R[k].y; ryy.y = R[k].y;   \
            ixx.x = I[k].x; ixx.y = I[k].x; iyy.x = I[k].y; iyy.y = I[k].y;   \
            v2f nR = CAr * rxx - CAi * ixx + CBr * ryy - CBi * iyy;           \
            v2f nI = CAi * rxx + CAr * ixx + CBi * ryy + CBr * iyy;           \
            R[k] = nR; I[k] = nI;                                             \
        } } while (0)

    #define GATE_CP_PAIR(c0, c1, A0, B0) do {                                 \
        v2f Ra = R[A0], Ia = I[A0], Rb = R[B0], Ib = I[B0];                   \
        R[A0] = c0.x * Ra - c0.y * Ia + c0.z * Rb - c0.w * Ib;                \
        I[A0] = c0.y * Ra + c0.x * Ia + c0.w * Rb + c0.z * Ib;                \
        R[B0] = c1.x * Ra - c1.y * Ia + c1.z * Rb - c1.w * Ib;                \
        I[B0] = c1.y * Ra + c1.x * Ia + c1.w * Rb + c1.z * Ib;                \
        } while (0)

    #define GATE_CP(BASE, A0, B0, A1, B1) do {                                \
        const float4 c0 = *(const float4*)(BASE);                             \
        const float4 c1 = *(const float4*)((BASE) + 4);                       \
        GATE_CP_PAIR(c0, c1, A0, B0);                                         \
        GATE_CP_PAIR(c0, c1, A1, B1);                                         \
        } while (0)

    #define GATE_DPP(BASE, SEL, CTRL) do {                                    \
        const float4 c = *(const float4*)((BASE) + ((SEL) ? 4 : 0));          \
        _Pragma("unroll")                                                     \
        for (int k = 0; k < 4; k++) {                                         \
            v2f vR = dppv<CTRL>(R[k]);                                        \
            v2f vI = dppv<CTRL>(I[k]);                                        \
            v2f nR = c.x * R[k] - c.y * I[k] + c.z * vR - c.w * vI;           \
            v2f nI = c.y * R[k] + c.x * I[k] + c.w * vR + c.z * vI;           \
            R[k] = nR; I[k] = nI;                                             \
        } } while (0)

    // ----------------- layers 1..5 -----------------
    #pragma unroll 1
    for (int l = 1; l < NL; l++) {
        const float* UL = &Umr[(l - 1) * 96];

        // arrA: q11 (in-pack), q10 (pack bit1), q9 (pack bit2),
        //       q8 (xor1), q7 (xor2), q5 (xor8)
        GATE_IP(UL + 11 * 8);
        GATE_CP(UL + 10 * 8, 0, 1, 2, 3);
        GATE_CP(UL +  9 * 8, 0, 2, 1, 3);
        GATE_DPP(UL + 8 * 8, t0, 0xB1);
        GATE_DPP(UL + 7 * 8, t1, 0x4E);
        GATE_DPP(UL + 5 * 8, t3, 0x128);

        // RT1: write phys-linear, read sigma
        {
            float2* w = &bufA[PwA];
            w[0] = make_float2(R[0].x, I[0].x);
            w[1] = make_float2(R[0].y, I[0].y);
            w[2] = make_float2(R[1].x, I[1].x);
            w[3] = make_float2(R[1].y, I[1].y);
            w[4] = make_float2(R[2].x, I[2].x);
            w[5] = make_float2(R[2].y, I[2].y);
            w[6] = make_float2(R[3].x, I[3].x);
            w[7] = make_float2(R[3].y, I[3].y);
            __syncthreads();
            #pragma unroll
            for (int m = 0; m < 8; m++) {
                const float2 v = bufA[Ps + SD[m]];
                if (m & 1) { R[m >> 1].y = v.x; I[m >> 1].y = v.y; }
                else       { R[m >> 1].x = v.x; I[m >> 1].x = v.y; }
            }
        }

        // arrB: q6 (in-pack), q4 (pack bit1), q3 (pack bit2),
        //       q2 (xor1), q1 (xor2), q0 (xor8)
        GATE_IP(UL + 6 * 8);
        GATE_CP(UL + 4 * 8, 0, 1, 2, 3);
        GATE_CP(UL + 3 * 8, 0, 2, 1, 3);
        GATE_DPP(UL + 2 * 8, t0, 0xB1);
        GATE_DPP(UL + 1 * 8, t1, 0x4E);
        GATE_DPP(UL + 0 * 8, t3, 0x128);

        // RT2: write at sigma addrs (restores phys-linear), read gmap (+CZ l=1,3)
        if (l < NL - 1) {
            #pragma unroll
            for (int m = 0; m < 8; m++) {
                float2 v;
                if (m & 1) { v.x = R[m >> 1].y; v.y = I[m >> 1].y; }
                else       { v.x = R[m >> 1].x; v.y = I[m >> 1].x; }
                bufB[Ps + SD[m]] = v;
            }
            __syncthreads();
            const bool czl = (l == 1) || (l == 3);
            #pragma unroll
            for (int m = 0; m < 8; m++) {
                float2 v = bufB[qm[m]];
                if (czl) { v.x *= czm[m]; v.y *= czm[m]; }
                if (m & 1) { R[m >> 1].y = v.x; I[m >> 1].y = v.y; }
                else       { R[m >> 1].x = v.x; I[m >> 1].x = v.y; }
            }
        }
    }
    #undef GATE_IP
    #undef GATE_CP
    #undef GATE_CP_PAIR
    #undef GATE_DPP

    // ----------------- measurement -----------------
    // regs: arrB layer 5, storage j=8t+m holds amp[sigma(j)] pre-ring5.
    // ring5 parities: z0 = par(t&0x1F7)^par(m); z1 = par(t&0xA); z2 = par(t&0xB).
    float p[8];
    p[0] = R[0].x * R[0].x + I[0].x * I[0].x;
    p[1] = R[0].y * R[0].y + I[0].y * I[0].y;
    p[2] = R[1].x * R[1].x + I[1].x * I[1].x;
    p[3] = R[1].y * R[1].y + I[1].y * I[1].y;
    p[4] = R[2].x * R[2].x + I[2].x * I[2].x;
    p[5] = R[2].y * R[2].y + I[2].y * I[2].y;
    p[6] = R[3].x * R[3].x + I[3].x * I[3].x;
    p[7] = R[3].y * R[3].y + I[3].y * I[3].y;
    float alt = (p[0] - p[1] - p[2] + p[3]) - (p[4] - p[5] - p[6] + p[7]);
    float tot = (p[0] + p[1] + p[2] + p[3]) + (p[4] + p[5] + p[6] + p[7]);
    float z0 = (__popc(t & 0x1F7) & 1) ? -alt : alt;
    float z1 = (__popc(t & 0x00A) & 1) ? -tot : tot;
    float z2 = (__popc(t & 0x00B) & 1) ? -tot : tot;

    #pragma unroll
    for (int off = 32; off > 0; off >>= 1) {
        z0 += __shfl_down(z0, off);
        z1 += __shfl_down(z1, off);
        z2 += __shfl_down(z2, off);
    }
    if ((t & 63) == 0) {
        zred[t >> 6][0] = z0;
        zred[t >> 6][1] = z1;
        zred[t >> 6][2] = z2;
    }
    __syncthreads();
    if (t == 0) {
        float q0 = 0.f, q1 = 0.f, q2 = 0.f;
        #pragma unroll
        for (int w = 0; w < 8; w++) {
            q0 += zred[w][0]; q1 += zred[w][1]; q2 += zred[w][2];
        }
        qv[0] = q0; qv[1] = q1; qv[2] = q2;
    }
    __syncthreads();

    // ----------------- back-end MLP -----------------
    if (t < 32) {
        float h = b4[t];
        h = fmaf(qv[0], W4[t * 3 + 0], h);
        h = fmaf(qv[1], W4[t * 3 + 1], h);
        h = fmaf(qv[2], W4[t * 3 + 2], h);
        h4s[t] = geluf(h);
    }
    __syncthreads();
    if (t < 64) {
        float acc = b5[t];
        #pragma unroll
        for (int h = 0; h < 32; h++) acc = fmaf(h4s[h], W5[t * 32 + h], acc);
        out[b * 64 + t] = acc;
    }
}

extern "C" void kernel_launch(void* const* d_in, const int* in_sizes, int n_in,
                              void* d_out, int out_size, void* d_ws, size_t ws_size,
                              hipStream_t stream) {
    (void)in_sizes; (void)n_in; (void)d_ws; (void)ws_size; (void)out_size;
    const float* x    = (const float*)d_in[0];
    const float* W1   = (const float*)d_in[1];
    const float* b1   = (const float*)d_in[2];
    const float* g_ln = (const float*)d_in[3];
    const float* b_ln = (const float*)d_in[4];
    const float* W2   = (const float*)d_in[5];
    const float* b2   = (const float*)d_in[6];
    const float* W3   = (const float*)d_in[7];
    const float* b3   = (const float*)d_in[8];
    const float* qw   = (const float*)d_in[9];
    const float* W4   = (const float*)d_in[10];
    const float* b4   = (const float*)d_in[11];
    const float* W5   = (const float*)d_in[12];
    const float* b5   = (const float*)d_in[13];
    float* out = (float*)d_out;

    qpu_kernel<<<BATCH, NT, 0, stream>>>(x, W1, b1, g_ln, b_ln, W2, b2,
                                         W3, b3, qw, W4, b4, W5, b5, out);
}